// Round 1
// baseline (1478.787 us; speedup 1.0000x reference)
//
#include <hip/hip_runtime.h>
#include <hip/hip_bf16.h>

#define N_NODES 50000
#define N_EDGES 1600000
#define ET (N_EDGES + N_NODES)
#define HID 128
#define N_LAYERS 4
#define EPS 1e-5f
#define NEG 0.2f
#define RB 256  // bn reduce blocks

__device__ __forceinline__ float leaky(float x) { return x >= 0.f ? x : NEG * x; }

// ---------------- CSR build (dst-sorted), runs once per launch ----------------
__global__ void zero_deg_kernel(int* __restrict__ deg) {
    int i = blockIdx.x * 256 + threadIdx.x;
    if (i < N_NODES) deg[i] = 0;
}

__global__ void hist_kernel(const int* __restrict__ ei, int* __restrict__ deg) {
    int e = blockIdx.x * 256 + threadIdx.x;
    if (e >= ET) return;
    int dst = (e < N_EDGES) ? ei[N_EDGES + e] : (e - N_EDGES);
    atomicAdd(&deg[dst], 1);
}

__global__ void scan_kernel(const int* __restrict__ deg, int* __restrict__ rowptr,
                            int* __restrict__ cursor) {
    __shared__ int sh[1024];
    int tid = threadIdx.x;
    const int CH = 49;  // 1024*49 >= 50000
    int base = tid * CH;
    int local = 0;
    for (int i = 0; i < CH; i++) {
        int idx = base + i;
        if (idx < N_NODES) local += deg[idx];
    }
    sh[tid] = local;
    __syncthreads();
    for (int off = 1; off < 1024; off <<= 1) {
        int v = (tid >= off) ? sh[tid - off] : 0;
        __syncthreads();
        sh[tid] += v;
        __syncthreads();
    }
    int run = (tid == 0) ? 0 : sh[tid - 1];
    for (int i = 0; i < CH; i++) {
        int idx = base + i;
        if (idx < N_NODES) {
            rowptr[idx] = run;
            cursor[idx] = run;
            run += deg[idx];
        }
    }
    if (tid == 1023) rowptr[N_NODES] = sh[1023];
}

__global__ void scatter_kernel(const int* __restrict__ ei, int* __restrict__ cursor,
                               int* __restrict__ csr_src) {
    int e = blockIdx.x * 256 + threadIdx.x;
    if (e >= ET) return;
    int src, dst;
    if (e < N_EDGES) { src = ei[e]; dst = ei[N_EDGES + e]; }
    else { src = dst = e - N_EDGES; }
    int pos = atomicAdd(&cursor[dst], 1);
    csr_src[pos] = src;
}

// ---------------- GEMM: xl = h@Wl, xr = h@Wr (blockIdx.y selects) ----------------
__global__ __launch_bounds__(256) void gemm_kernel(const float* __restrict__ hin,
                                                   const float* __restrict__ Wl,
                                                   const float* __restrict__ Wr,
                                                   float* __restrict__ xl,
                                                   float* __restrict__ xr) {
    __shared__ float Wsh[128 * 128];
    __shared__ float Hsh[32][128];
    const float* __restrict__ W = blockIdx.y ? Wr : Wl;
    float* __restrict__ out = blockIdx.y ? xr : xl;
    int row0 = blockIdx.x * 32;
    int tid = threadIdx.x;
    for (int i = tid; i < 4096; i += 256)
        ((float4*)Wsh)[i] = ((const float4*)W)[i];
    for (int i = tid; i < 1024; i += 256) {
        int r = i >> 5, c4 = i & 31;
        int gr = row0 + r;
        float4 v;
        if (gr < N_NODES) v = ((const float4*)(hin + (size_t)gr * HID))[c4];
        else v = make_float4(0.f, 0.f, 0.f, 0.f);
        ((float4*)(&Hsh[r][0]))[c4] = v;
    }
    __syncthreads();
    int colv = tid & 31;        // float4 column index (cols 4*colv..+3)
    int rowg = (tid >> 5) * 4;  // 4 rows per thread
    float4 a0 = make_float4(0.f, 0.f, 0.f, 0.f), a1 = a0, a2 = a0, a3 = a0;
#pragma unroll 4
    for (int k = 0; k < 128; k++) {
        float4 w = ((const float4*)(&Wsh[k * 128]))[colv];
        float h0 = Hsh[rowg][k], h1 = Hsh[rowg + 1][k];
        float h2 = Hsh[rowg + 2][k], h3 = Hsh[rowg + 3][k];
        a0.x += h0 * w.x; a0.y += h0 * w.y; a0.z += h0 * w.z; a0.w += h0 * w.w;
        a1.x += h1 * w.x; a1.y += h1 * w.y; a1.z += h1 * w.z; a1.w += h1 * w.w;
        a2.x += h2 * w.x; a2.y += h2 * w.y; a2.z += h2 * w.z; a2.w += h2 * w.w;
        a3.x += h3 * w.x; a3.y += h3 * w.y; a3.z += h3 * w.z; a3.w += h3 * w.w;
    }
    int gr0 = row0 + rowg;
    if (gr0 + 0 < N_NODES) ((float4*)(out + (size_t)(gr0 + 0) * HID))[colv] = a0;
    if (gr0 + 1 < N_NODES) ((float4*)(out + (size_t)(gr0 + 1) * HID))[colv] = a1;
    if (gr0 + 2 < N_NODES) ((float4*)(out + (size_t)(gr0 + 2) * HID))[colv] = a2;
    if (gr0 + 3 < N_NODES) ((float4*)(out + (size_t)(gr0 + 3) * HID))[colv] = a3;
}

// ---------------- Edge aggregation: one wave per dst node, online softmax ----------------
__global__ __launch_bounds__(256) void aggregate_kernel(
    const float* __restrict__ xl, const float* __restrict__ xr,
    const float* __restrict__ att, const float* __restrict__ bias,
    const int* __restrict__ rowptr, const int* __restrict__ csr_src,
    float* __restrict__ hout) {
    int node = blockIdx.x * 4 + (threadIdx.x >> 6);
    if (node >= N_NODES) return;
    int lane = threadIdx.x & 63;
    int c0 = lane * 2;
    float a0 = att[c0], a1 = att[c0 + 1];
    const float2 xr2 = *(const float2*)(xr + (size_t)node * HID + c0);
    float r0 = xr2.x, r1 = xr2.y;
    int beg = rowptr[node], end = rowptr[node + 1];
    float m = -INFINITY, s = 0.f, acc0 = 0.f, acc1 = 0.f;
    for (int base = beg; base < end; base += 64) {
        int n = end - base;
        if (n > 64) n = 64;
        int my = (lane < n) ? csr_src[base + lane] : 0;
        for (int j = 0; j < n; j++) {
            int src = __shfl(my, j, 64);
            const float2 v2 = *(const float2*)(xl + (size_t)src * HID + c0);
            float v0 = v2.x, v1 = v2.y;
            float t = leaky(v0 + r0) * a0 + leaky(v1 + r1) * a1;
#pragma unroll
            for (int off = 32; off; off >>= 1) t += __shfl_xor(t, off, 64);
            if (t > m) {
                float c = __expf(m - t);  // first iter: exp(-inf)=0 zeroes s/acc
                s *= c; acc0 *= c; acc1 *= c;
                m = t;
            }
            float w = __expf(t - m);
            s += w;
            acc0 += w * v0;
            acc1 += w * v1;
        }
    }
    float inv = 1.f / s;
    hout[(size_t)node * HID + c0] = acc0 * inv + bias[c0];
    hout[(size_t)node * HID + c0 + 1] = acc1 * inv + bias[c0 + 1];
}

// ---------------- BatchNorm ----------------
__global__ __launch_bounds__(256) void bn_reduce_kernel(const float* __restrict__ h,
                                                        float* __restrict__ part) {
    int tid = threadIdx.x;
    int c = tid & 127, half = tid >> 7;
    float s = 0.f, q = 0.f;
    for (int r = blockIdx.x * 2 + half; r < N_NODES; r += RB * 2) {
        float v = h[(size_t)r * HID + c];
        s += v; q += v * v;
    }
    __shared__ float shs[256], shq[256];
    shs[tid] = s; shq[tid] = q;
    __syncthreads();
    if (half == 0) {
        part[blockIdx.x * 256 + c] = s + shs[tid + 128];
        part[blockIdx.x * 256 + 128 + c] = q + shq[tid + 128];
    }
}

__global__ void bn_finalize_kernel(const float* __restrict__ part, float* __restrict__ mu,
                                   float* __restrict__ rstd) {
    int c = threadIdx.x;  // 128 threads
    float s = 0.f, q = 0.f;
    for (int b = 0; b < RB; b++) {
        s += part[b * 256 + c];
        q += part[b * 256 + 128 + c];
    }
    float m = s / (float)N_NODES;
    float v = q / (float)N_NODES - m * m;
    if (v < 0.f) v = 0.f;
    mu[c] = m;
    rstd[c] = rsqrtf(v + EPS);
}

__global__ __launch_bounds__(256) void bn_norm_kernel(float* __restrict__ h,
                                                      const float* __restrict__ mu,
                                                      const float* __restrict__ rstd,
                                                      const float* __restrict__ gamma,
                                                      const float* __restrict__ beta,
                                                      float* __restrict__ acc, int first) {
    int idx = blockIdx.x * 256 + threadIdx.x;
    if (idx >= N_NODES * HID) return;
    int c = idx & 127;
    float v = (h[idx] - mu[c]) * rstd[c] * gamma[c] + beta[c];
    h[idx] = v;
    float a = 0.2f * v;  // resw = 1/(N_LAYERS+1)
    acc[idx] = first ? a : acc[idx] + a;
}

// ---------------- Decode: per-pair dot product ----------------
__global__ __launch_bounds__(256) void predict_kernel(const float* __restrict__ acc,
                                                      const int* __restrict__ eli,
                                                      float* __restrict__ out) {
    int p = blockIdx.x * 4 + (threadIdx.x >> 6);
    if (p >= 8192) return;
    int lane = threadIdx.x & 63;
    int i = eli[p], j = eli[8192 + p];
    const float2 va = *(const float2*)(acc + (size_t)i * HID + lane * 2);
    const float2 vb = *(const float2*)(acc + (size_t)j * HID + lane * 2);
    float t = va.x * vb.x + va.y * vb.y;
#pragma unroll
    for (int off = 32; off; off >>= 1) t += __shfl_xor(t, off, 64);
    if (lane == 0) out[p] = t;
}

extern "C" void kernel_launch(void* const* d_in, const int* in_sizes, int n_in,
                              void* d_out, int out_size, void* d_ws, size_t ws_size,
                              hipStream_t stream) {
    const float* x = (const float*)d_in[0];
    const int* ei = (const int*)d_in[1];
    const int* eli = (const int*)d_in[2];
    const float* Wl = (const float*)d_in[3];
    const float* Wr = (const float*)d_in[4];
    const float* att = (const float*)d_in[5];
    const float* bias = (const float*)d_in[6];
    const float* gamma = (const float*)d_in[7];
    const float* beta = (const float*)d_in[8];
    float* out = (float*)d_out;

    char* ws = (char*)d_ws;
    size_t off = 0;
    float* hbuf = (float*)(ws + off); off += (size_t)N_NODES * HID * 4;   // 25.6 MB
    float* xl   = (float*)(ws + off); off += (size_t)N_NODES * HID * 4;   // 25.6 MB
    float* xr   = (float*)(ws + off); off += (size_t)N_NODES * HID * 4;   // 25.6 MB
    float* accb = (float*)(ws + off); off += (size_t)N_NODES * HID * 4;   // 25.6 MB
    int* rowptr = (int*)(ws + off);   off += ((size_t)(N_NODES + 1) * 4 + 31) & ~31ul;
    int* deg    = (int*)(ws + off);   off += (size_t)N_NODES * 4;
    int* cursor = (int*)(ws + off);   off += (size_t)N_NODES * 4;
    int* csr_src = (int*)(ws + off);  off += (size_t)ET * 4;
    float* part = (float*)(ws + off); off += (size_t)RB * 256 * 4;
    float* mu   = (float*)(ws + off); off += 128 * 4;
    float* rstd = (float*)(ws + off); off += 128 * 4;

    // CSR build (dst-sorted); topology is fixed across layers
    zero_deg_kernel<<<(N_NODES + 255) / 256, 256, 0, stream>>>(deg);
    hist_kernel<<<(ET + 255) / 256, 256, 0, stream>>>(ei, deg);
    scan_kernel<<<1, 1024, 0, stream>>>(deg, rowptr, cursor);
    scatter_kernel<<<(ET + 255) / 256, 256, 0, stream>>>(ei, cursor, csr_src);

    for (int l = 0; l < N_LAYERS; l++) {
        const float* hin = (l == 0) ? x : hbuf;
        gemm_kernel<<<dim3((N_NODES + 31) / 32, 2), 256, 0, stream>>>(
            hin, Wl + (size_t)l * HID * HID, Wr + (size_t)l * HID * HID, xl, xr);
        aggregate_kernel<<<(N_NODES + 3) / 4, 256, 0, stream>>>(
            xl, xr, att + l * HID, bias + l * HID, rowptr, csr_src, hbuf);
        bn_reduce_kernel<<<RB, 256, 0, stream>>>(hbuf, part);
        bn_finalize_kernel<<<1, 128, 0, stream>>>(part, mu, rstd);
        bn_norm_kernel<<<(N_NODES * HID + 255) / 256, 256, 0, stream>>>(
            hbuf, mu, rstd, gamma + l * HID, beta + l * HID, accb, l == 0 ? 1 : 0);
    }
    predict_kernel<<<8192 / 4, 256, 0, stream>>>(accb, eli, out);
}